// Round 2
// baseline (156.796 us; speedup 1.0000x reference)
//
#include <hip/hip_runtime.h>
#include <hip/hip_bf16.h>

#define FULL_DIM 4096
#define EXPERT_DIM 1024
#define SLICE 512
#define S0 (3*SLICE)
#define GATE_HID 128
#define P_TOK 4096
#define BATCH 4
#define NCONV 1600   // (3*1024*512 + 128*512) elems / (256 thr * 4)

typedef __bf16 bf16;
typedef __bf16 bf16x4 __attribute__((ext_vector_type(4)));
typedef __bf16 bf16x8 __attribute__((ext_vector_type(8)));
typedef float f32x4 __attribute__((ext_vector_type(4)));

__device__ inline void gl_lds16(const void* g, void* l) {
    __builtin_amdgcn_global_load_lds((const __attribute__((address_space(1))) void*)g,
                                     (__attribute__((address_space(3))) void*)l, 16, 0, 0);
}

// ============ kernel A: weight converts + mask/compact + affinity weights ============
// blocks [0,NCONV): f32->bf16 converts of wq|wk|wv -> wqkvb and gw1 -> w1b
// block NCONV: fingerprint mask + index compaction
// blocks NCONV+1 / NCONV+2: cw[v,k] = sum_d dirs[v,d] * w[d,k]  (wk -> rows 0..4, wq -> rows 5..9)
__global__ void k_setup(const float* __restrict__ wq, const float* __restrict__ wk,
                        const float* __restrict__ wv, const float* __restrict__ gw1,
                        const float* __restrict__ penta, const float* __restrict__ fp,
                        bf16* __restrict__ wqkvb, bf16* __restrict__ w1b,
                        bf16* __restrict__ cwb, float* __restrict__ mask_out,
                        int* __restrict__ idx) {
    __shared__ float dirs[5][1024];
    __shared__ float red[5][4];
    __shared__ int offs[256];
    const int bid = blockIdx.x, t = threadIdx.x;
    if (bid < NCONV) {
        int i = bid * 1024 + t * 4;
        if (i < 3 * 524288) {
            const float* src = (i < 524288) ? wq : (i < 2 * 524288 ? wk : wv);
            float4 v = *(const float4*)(src + (i & 524287));
            bf16x4 b = { (bf16)v.x, (bf16)v.y, (bf16)v.z, (bf16)v.w };
            *(bf16x4*)(wqkvb + i) = b;
        } else {
            int j = i - 3 * 524288;
            float4 v = *(const float4*)(gw1 + j);
            bf16x4 b = { (bf16)v.x, (bf16)v.y, (bf16)v.z, (bf16)v.w };
            *(bf16x4*)(w1b + j) = b;
        }
        return;
    }
    if (bid == NCONV) {
        // mask + compaction
        int base = t * 16;
        unsigned bits = 0;
        int c = 0;
#pragma unroll
        for (int i = 0; i < 16; i++) {
            float v = fp[base + i];
            bool m = (v >= 0.375f) && (v < 0.5f);
            mask_out[base + i] = m ? 1.0f : 0.0f;
            bits |= ((unsigned)m) << i;
            c += (int)m;
        }
        offs[t] = c;
        __syncthreads();
        if (t == 0) {
            int s = 0;
            for (int i = 0; i < 256; i++) { int cc = offs[i]; offs[i] = s; s += cc; }
        }
        __syncthreads();
        int o = offs[t];
#pragma unroll
        for (int i = 0; i < 16; i++)
            if (bits & (1u << i)) idx[o++] = base + i;
        return;
    }
    // affinity-weight blocks
    {
        int lane = t & 63, wave = t >> 6;
#pragma unroll
        for (int v = 0; v < 5; v++) {
            float s = 0.f;
#pragma unroll
            for (int i = 0; i < 4; i++) { float x = penta[v * 1024 + t + i * 256]; s += x * x; }
            for (int d = 32; d; d >>= 1) s += __shfl_xor(s, d);
            if (lane == 0) red[v][wave] = s;
        }
        __syncthreads();
#pragma unroll
        for (int v = 0; v < 5; v++) {
            float inv = rsqrtf(red[v][0] + red[v][1] + red[v][2] + red[v][3]);
#pragma unroll
            for (int i = 0; i < 4; i++) {
                int c = t + i * 256;
                dirs[v][c] = penta[v * 1024 + c] * inv;
            }
        }
        __syncthreads();
        const float* w = (bid == NCONV + 1) ? wk : wq;
        int vbase = (bid == NCONV + 1) ? 0 : 5;
#pragma unroll
        for (int half = 0; half < 2; half++) {
            int c = half * 256 + t;
            float acc[5] = {0, 0, 0, 0, 0};
            for (int d = 0; d < 1024; d += 4) {
                float x0 = w[(size_t)(d + 0) * 512 + c];
                float x1 = w[(size_t)(d + 1) * 512 + c];
                float x2 = w[(size_t)(d + 2) * 512 + c];
                float x3 = w[(size_t)(d + 3) * 512 + c];
#pragma unroll
                for (int v = 0; v < 5; v++)
                    acc[v] += x0 * dirs[v][d] + x1 * dirs[v][d + 1]
                            + x2 * dirs[v][d + 2] + x3 * dirs[v][d + 3];
            }
#pragma unroll
            for (int v = 0; v < 5; v++) cwb[(size_t)(vbase + v) * 512 + c] = (bf16)acc[v];
        }
        // zero pad rows of cwb (rows 10..15), split across the two blocks
        int zr = 10 + (bid - (NCONV + 1)) * 3;
        for (int e = t; e < 3 * 512; e += 256) cwb[(size_t)zr * 512 + e] = (bf16)0.f;
    }
}

// ============ kernel B: gather + gate MLP + scale, 32 rows/block ============
__launch_bounds__(256)
__global__ void k_gate(const float* __restrict__ tokens, const int* __restrict__ idx,
                       const bf16* __restrict__ w1b, const float* __restrict__ gb1,
                       const float* __restrict__ gw2, const float* __restrict__ gb2,
                       const float* __restrict__ alpha, int p, int M,
                       bf16* __restrict__ Fs) {
    __shared__ bf16 F[32][520];     // padded: 2-way bank max
    __shared__ bf16 W1[128][72];    // padded
    __shared__ float H[32][132];
    __shared__ int trow[32];
    __shared__ float scl[32];
    const int t = threadIdx.x, wave = t >> 6, lane = t & 63;
    const int fr = lane & 15, fq = lane >> 4;
    const int m0 = blockIdx.x * 32;

    if (t < 32) {
        int m = m0 + t;
        int r = -1;
        if (m < M) { int b = m / p; int j = m - b * p; r = b * P_TOK + idx[j]; }
        trow[t] = r;
    }
    __syncthreads();
    // gather expert slice -> bf16 LDS
#pragma unroll
    for (int it = 0; it < 16; it++) {
        int r = it * 2 + (t >> 7);
        int c4 = (t & 127) * 4;
        int tr = trow[r];
        float4 v = {0.f, 0.f, 0.f, 0.f};
        if (tr >= 0) v = *(const float4*)(tokens + (size_t)tr * FULL_DIM + S0 + c4);
        bf16x4 b = { (bf16)v.x, (bf16)v.y, (bf16)v.z, (bf16)v.w };
        *(bf16x4*)(&F[r][c4]) = b;
    }
    __syncthreads();
    // gate layer 1: H = GELU(F @ w1^T + b1) via MFMA (wave -> 32 cols, 32 rows)
    f32x4 acc[2][2];
#pragma unroll
    for (int i = 0; i < 2; i++)
#pragma unroll
        for (int j = 0; j < 2; j++) acc[i][j] = (f32x4){0.f, 0.f, 0.f, 0.f};
    for (int k0 = 0; k0 < 512; k0 += 64) {
        {
            int n = t >> 1, ch = (t & 1) * 32;
            const bf16* src = w1b + (size_t)n * 512 + k0 + ch;
#pragma unroll
            for (int q = 0; q < 4; q++)
                *(bf16x8*)(&W1[n][ch + q * 8]) = *(const bf16x8*)(src + q * 8);
        }
        __syncthreads();
#pragma unroll
        for (int ks = 0; ks < 2; ks++) {
            bf16x8 a0 = *(const bf16x8*)(&F[fr][k0 + ks * 32 + fq * 8]);
            bf16x8 a1 = *(const bf16x8*)(&F[16 + fr][k0 + ks * 32 + fq * 8]);
            bf16x8 b0 = *(const bf16x8*)(&W1[wave * 32 + fr][ks * 32 + fq * 8]);
            bf16x8 b1 = *(const bf16x8*)(&W1[wave * 32 + 16 + fr][ks * 32 + fq * 8]);
            acc[0][0] = __builtin_amdgcn_mfma_f32_16x16x32_bf16(a0, b0, acc[0][0], 0, 0, 0);
            acc[0][1] = __builtin_amdgcn_mfma_f32_16x16x32_bf16(a0, b1, acc[0][1], 0, 0, 0);
            acc[1][0] = __builtin_amdgcn_mfma_f32_16x16x32_bf16(a1, b0, acc[1][0], 0, 0, 0);
            acc[1][1] = __builtin_amdgcn_mfma_f32_16x16x32_bf16(a1, b1, acc[1][1], 0, 0, 0);
        }
        __syncthreads();
    }
    // epilogue: bias + exact GELU into H
#pragma unroll
    for (int mi = 0; mi < 2; mi++)
#pragma unroll
        for (int ni = 0; ni < 2; ni++) {
            int col = wave * 32 + ni * 16 + fr;
            float bias = gb1[col];
#pragma unroll
            for (int r = 0; r < 4; r++) {
                int row = mi * 16 + fq * 4 + r;
                float v = acc[mi][ni][r] + bias;
                H[row][col] = 0.5f * v * (1.0f + erff(v * 0.70710678118f));
            }
        }
    __syncthreads();
    // gate layer 2 + sigmoid -> per-row scale
    {
        int r = wave * 8 + (lane >> 3), g = lane & 7;
        float s = 0.f;
#pragma unroll
        for (int i = 0; i < 16; i++) { int c = g + i * 8; s += H[r][c] * gw2[c]; }
        s += __shfl_xor(s, 1); s += __shfl_xor(s, 2); s += __shfl_xor(s, 4);
        if (g == 0) {
            float aw = 1.0f / (1.0f + expf(-alpha[0]));
            float gt = 1.0f / (1.0f + expf(-(s + gb2[0])));
            scl[r] = gt * aw + (1.0f - aw);
        }
    }
    __syncthreads();
    // scale features, write Fs (bf16)
#pragma unroll
    for (int it = 0; it < 16; it++) {
        int r = it * 2 + (t >> 7);
        int c4 = (t & 127) * 4;
        bf16x4 b = *(const bf16x4*)(&F[r][c4]);
        float sc = scl[r];
        bf16x4 o = { (bf16)((float)b[0] * sc), (bf16)((float)b[1] * sc),
                     (bf16)((float)b[2] * sc), (bf16)((float)b[3] * sc) };
        *(bf16x4*)(Fs + (size_t)(m0 + r) * 512 + c4) = o;
    }
}

// ============ kernel C: QKV GEMM, N=3072 merged, 2-phase double-buffered ============
__launch_bounds__(256)
__global__ void k_qkv(const bf16* __restrict__ A, const bf16* __restrict__ W,
                      float* __restrict__ out, int M) {
    __shared__ bf16 As[2][128 * 32];
    __shared__ bf16 Bs[2][128 * 32];
    const int t = threadIdx.x, wave = t >> 6, lane = t & 63;
    const int fr = lane & 15, fq = lane >> 4;
    const int m0 = blockIdx.x * 128, n0 = blockIdx.y * 128;
    const int wr = wave >> 1, wc = wave & 1;

    f32x4 acc[4][4];
#pragma unroll
    for (int i = 0; i < 4; i++)
#pragma unroll
        for (int j = 0; j < 4; j++) acc[i][j] = (f32x4){0.f, 0.f, 0.f, 0.f};

    const bf16* ga = A + (size_t)(m0 + (t >> 2)) * 512 + (t & 3) * 8;
    const bf16* gb = W + (size_t)(n0 + (t >> 2)) * 512 + (t & 3) * 8;

#define STAGE(buf, ko)                                              \
    gl_lds16(ga + (ko),            &As[buf][wave * 512]);           \
    gl_lds16(ga + (ko) + 64 * 512, &As[buf][2048 + wave * 512]);    \
    gl_lds16(gb + (ko),            &Bs[buf][wave * 512]);           \
    gl_lds16(gb + (ko) + 64 * 512, &Bs[buf][2048 + wave * 512]);

    STAGE(0, 0);
    __syncthreads();
    int cur = 0;
    for (int kt = 0; kt < 16; kt++) {
        if (kt < 15) { STAGE(cur ^ 1, (kt + 1) * 32); }
        bf16x8 af[4], bw[4];
#pragma unroll
        for (int mi = 0; mi < 4; mi++)
            af[mi] = *(const bf16x8*)(&As[cur][(wr * 64 + mi * 16 + fr) * 32 + fq * 8]);
#pragma unroll
        for (int ni = 0; ni < 4; ni++)
            bw[ni] = *(const bf16x8*)(&Bs[cur][(wc * 64 + ni * 16 + fr) * 32 + fq * 8]);
#pragma unroll
        for (int mi = 0; mi < 4; mi++)
#pragma unroll
            for (int ni = 0; ni < 4; ni++)
                acc[mi][ni] = __builtin_amdgcn_mfma_f32_16x16x32_bf16(af[mi], bw[ni], acc[mi][ni], 0, 0, 0);
        __syncthreads();
        cur ^= 1;
    }
#undef STAGE

    const int z = blockIdx.y >> 3;
    const int nb = (blockIdx.y & 7) * 128;
    float* obase = out + (size_t)z * M * EXPERT_DIM;
#pragma unroll
    for (int mi = 0; mi < 4; mi++)
#pragma unroll
        for (int ni = 0; ni < 4; ni++) {
            int col = nb + wc * 64 + ni * 16 + fr;
#pragma unroll
            for (int r = 0; r < 4; r++) {
                int row = m0 + wr * 64 + mi * 16 + fq * 4 + r;
                if (row < M) obase[(size_t)row * EXPERT_DIM + col] = acc[mi][ni][r];
            }
        }
}

// ============ kernel D: affinities via Fs @ cw^T (tiny MFMA GEMM) ============
__global__ void k_aff(const bf16* __restrict__ Fs, const bf16* __restrict__ cwb,
                      float* __restrict__ aff, int M) {
    const int t = threadIdx.x, wave = t >> 6, lane = t & 63;
    const int fr = lane & 15, fq = lane >> 4;
    const int m0 = blockIdx.x * 128 + wave * 32;
    f32x4 acc[2];
    acc[0] = (f32x4){0.f, 0.f, 0.f, 0.f};
    acc[1] = (f32x4){0.f, 0.f, 0.f, 0.f};
    for (int k0 = 0; k0 < 512; k0 += 32) {
        bf16x8 b  = *(const bf16x8*)(cwb + (size_t)fr * 512 + k0 + fq * 8);
        bf16x8 a0 = *(const bf16x8*)(Fs + (size_t)(m0 + fr) * 512 + k0 + fq * 8);
        bf16x8 a1 = *(const bf16x8*)(Fs + (size_t)(m0 + 16 + fr) * 512 + k0 + fq * 8);
        acc[0] = __builtin_amdgcn_mfma_f32_16x16x32_bf16(a0, b, acc[0], 0, 0, 0);
        acc[1] = __builtin_amdgcn_mfma_f32_16x16x32_bf16(a1, b, acc[1], 0, 0, 0);
    }
    int v = fr;  // output col = affinity row (0..4 K, 5..9 Q, 10..15 pad)
    if (v < 10) {
#pragma unroll
        for (int mi = 0; mi < 2; mi++)
#pragma unroll
            for (int r = 0; r < 4; r++) {
                int m = m0 + mi * 16 + fq * 4 + r;
                if (m < M) aff[(size_t)v * M + m] = acc[mi][r];
            }
    }
}

extern "C" void kernel_launch(void* const* d_in, const int* in_sizes, int n_in,
                              void* d_out, int out_size, void* d_ws, size_t ws_size,
                              hipStream_t stream) {
    const float* tokens = (const float*)d_in[0];
    const float* fps    = (const float*)d_in[1];
    const float* alpha  = (const float*)d_in[2];
    const float* gw1    = (const float*)d_in[3];
    const float* gb1    = (const float*)d_in[4];
    const float* gw2    = (const float*)d_in[5];
    const float* gb2    = (const float*)d_in[6];
    const float* wq     = (const float*)d_in[7];
    const float* wk     = (const float*)d_in[8];
    const float* wv     = (const float*)d_in[9];
    const float* penta  = (const float*)d_in[10];
    float* out = (float*)d_out;

    int p = (out_size - P_TOK) / (3 * BATCH * EXPERT_DIM + 2 * 5 * BATCH);  // 12328
    if (p <= 0) return;
    int M = BATCH * p;
    int Mpad = (M + 127) & ~127;

    char* ws = (char*)d_ws;
    size_t off = 0;
    int*  idx   = (int*)(ws + off);  off += 16 * 1024;
    bf16* wqkvb = (bf16*)(ws + off); off += (size_t)3 * EXPERT_DIM * SLICE * 2;
    bf16* w1b   = (bf16*)(ws + off); off += (size_t)GATE_HID * SLICE * 2;
    bf16* cwb   = (bf16*)(ws + off); off += 16 * 512 * 2;
    bf16* Fs    = (bf16*)(ws + off); off += (size_t)Mpad * SLICE * 2;
    (void)ws_size;

    float* aff_out  = out + (size_t)3 * M * EXPERT_DIM;
    float* mask_out = aff_out + (size_t)10 * M;

    k_setup<<<NCONV + 3, 256, 0, stream>>>(wq, wk, wv, gw1, penta, fps,
                                           wqkvb, w1b, cwb, mask_out, idx);
    k_gate<<<Mpad / 32, 256, 0, stream>>>(tokens, idx, w1b, gb1, gw2, gb2, alpha, p, M, Fs);
    k_qkv<<<dim3(Mpad / 128, 24), 256, 0, stream>>>(Fs, wqkvb, out, M);
    k_aff<<<Mpad / 128, 256, 0, stream>>>(Fs, cwb, aff_out, M);
}

// Round 4
// 59.607 us; speedup vs baseline: 2.6305x; 2.6305x over previous
//
#include <hip/hip_runtime.h>
#include <hip/hip_bf16.h>

#define FULL_DIM 4096
#define EXPERT_DIM 1024
#define SLICE 512
#define S0 (3*SLICE)
#define GATE_HID 128
#define P_TOK 4096
#define BATCH 4
#define NCONV 1600   // (3*1024*512 + 128*512) elems / (256 thr * 4)
#define NCW 16       // cw partial blocks (64 d-values each)

typedef __bf16 bf16;
typedef __bf16 bf16x4 __attribute__((ext_vector_type(4)));
typedef __bf16 bf16x8 __attribute__((ext_vector_type(8)));
typedef float f32x4 __attribute__((ext_vector_type(4)));

__device__ inline void gl_lds16(const void* g, void* l) {
    __builtin_amdgcn_global_load_lds((const __attribute__((address_space(1))) void*)g,
                                     (__attribute__((address_space(3))) void*)l, 16, 0, 0);
}

// ============ kernel A: converts + mask/compact + cw partials ============
__global__ void k_setup(const float* __restrict__ wq, const float* __restrict__ wk,
                        const float* __restrict__ wv, const float* __restrict__ gw1,
                        const float* __restrict__ penta, const float* __restrict__ fp,
                        bf16* __restrict__ wqkvb, bf16* __restrict__ w1b,
                        float* __restrict__ cwp, float* __restrict__ mask_out,
                        int* __restrict__ idx) {
    __shared__ float sd[5][64];
    __shared__ float red[5][4];
    __shared__ int offs[256];
    const int bid = blockIdx.x, t = threadIdx.x;
    if (bid < NCONV) {
        int i = bid * 1024 + t * 4;
        if (i < 3 * 524288) {
            const float* src = (i < 524288) ? wq : (i < 2 * 524288 ? wk : wv);
            float4 v = *(const float4*)(src + (i & 524287));
            bf16x4 b = { (bf16)v.x, (bf16)v.y, (bf16)v.z, (bf16)v.w };
            *(bf16x4*)(wqkvb + i) = b;
        } else {
            int j = i - 3 * 524288;
            float4 v = *(const float4*)(gw1 + j);
            bf16x4 b = { (bf16)v.x, (bf16)v.y, (bf16)v.z, (bf16)v.w };
            *(bf16x4*)(w1b + j) = b;
        }
        return;
    }
    if (bid == NCONV) {
        int base = t * 16;
        unsigned bits = 0;
        int c = 0;
#pragma unroll
        for (int i = 0; i < 16; i++) {
            float v = fp[base + i];
            bool m = (v >= 0.375f) && (v < 0.5f);
            mask_out[base + i] = m ? 1.0f : 0.0f;
            bits |= ((unsigned)m) << i;
            c += (int)m;
        }
        offs[t] = c;
        __syncthreads();
        if (t == 0) {
            int s = 0;
            for (int i = 0; i < 256; i++) { int cc = offs[i]; offs[i] = s; s += cc; }
        }
        __syncthreads();
        int o = offs[t];
#pragma unroll
        for (int i = 0; i < 16; i++)
            if (bits & (1u << i)) idx[o++] = base + i;
        return;
    }
    // ---- cw partial block ----
    {
        const int cb = bid - (NCONV + 1);     // 0..15
        const int d0 = cb * 64;
        const int lane = t & 63, wave = t >> 6;
        // norms of pentachoron rows
#pragma unroll
        for (int v = 0; v < 5; v++) {
            float s = 0.f;
#pragma unroll
            for (int i = 0; i < 4; i++) { float x = penta[v * 1024 + t + i * 256]; s += x * x; }
            for (int d = 32; d; d >>= 1) s += __shfl_xor(s, d);
            if (lane == 0) red[v][wave] = s;
        }
        __syncthreads();
        // normalized dirs chunk into LDS (320 entries > 256 threads: strided!)
        for (int e = t; e < 5 * 64; e += 256) {
            int v = e >> 6, dd = e & 63;
            float inv = rsqrtf(red[v][0] + red[v][1] + red[v][2] + red[v][3]);
            sd[v][dd] = penta[v * 1024 + d0 + dd] * inv;
        }
        __syncthreads();
#pragma unroll
        for (int pass = 0; pass < 2; pass++) {
            int col = pass * 256 + t;
            float aK[5] = {0, 0, 0, 0, 0}, aQ[5] = {0, 0, 0, 0, 0};
            for (int d = 0; d < 64; d += 4) {
#pragma unroll
                for (int u = 0; u < 4; u++) {
                    float kv = wk[(size_t)(d0 + d + u) * 512 + col];
                    float qv = wq[(size_t)(d0 + d + u) * 512 + col];
                    float dv;
#pragma unroll
                    for (int v = 0; v < 5; v++) {
                        dv = sd[v][d + u];
                        aK[v] += dv * kv;
                        aQ[v] += dv * qv;
                    }
                }
            }
#pragma unroll
            for (int v = 0; v < 5; v++) {
                cwp[((size_t)cb * 10 + v) * 512 + col] = aK[v];
                cwp[((size_t)cb * 10 + 5 + v) * 512 + col] = aQ[v];
            }
        }
    }
}

// ============ kernel B: gather + gate MLP + scale, 32 rows/block ============
__launch_bounds__(256)
__global__ void k_gate(const float* __restrict__ tokens, const int* __restrict__ idx,
                       const bf16* __restrict__ w1b, const float* __restrict__ gb1,
                       const float* __restrict__ gw2, const float* __restrict__ gb2,
                       const float* __restrict__ alpha, int p, int M,
                       bf16* __restrict__ Fs) {
    __shared__ bf16 F[32][520];
    __shared__ bf16 W1[128][72];
    __shared__ float H[32][132];
    __shared__ int trow[32];
    __shared__ float scl[32];
    const int t = threadIdx.x, wave = t >> 6, lane = t & 63;
    const int fr = lane & 15, fq = lane >> 4;
    const int m0 = blockIdx.x * 32;

    if (t < 32) {
        int m = m0 + t;
        int r = -1;
        if (m < M) { int b = m / p; int j = m - b * p; r = b * P_TOK + idx[j]; }
        trow[t] = r;
    }
    __syncthreads();
#pragma unroll
    for (int it = 0; it < 16; it++) {
        int r = it * 2 + (t >> 7);
        int c4 = (t & 127) * 4;
        int tr = trow[r];
        float4 v = {0.f, 0.f, 0.f, 0.f};
        if (tr >= 0) v = *(const float4*)(tokens + (size_t)tr * FULL_DIM + S0 + c4);
        bf16x4 b = { (bf16)v.x, (bf16)v.y, (bf16)v.z, (bf16)v.w };
        *(bf16x4*)(&F[r][c4]) = b;
    }
    __syncthreads();
    f32x4 acc[2][2];
#pragma unroll
    for (int i = 0; i < 2; i++)
#pragma unroll
        for (int j = 0; j < 2; j++) acc[i][j] = (f32x4){0.f, 0.f, 0.f, 0.f};
    for (int k0 = 0; k0 < 512; k0 += 64) {
        {
            int n = t >> 1, ch = (t & 1) * 32;
            const bf16* src = w1b + (size_t)n * 512 + k0 + ch;
#pragma unroll
            for (int q = 0; q < 4; q++)
                *(bf16x8*)(&W1[n][ch + q * 8]) = *(const bf16x8*)(src + q * 8);
        }
        __syncthreads();
#pragma unroll
        for (int ks = 0; ks < 2; ks++) {
            bf16x8 a0 = *(const bf16x8*)(&F[fr][k0 + ks * 32 + fq * 8]);
            bf16x8 a1 = *(const bf16x8*)(&F[16 + fr][k0 + ks * 32 + fq * 8]);
            bf16x8 b0 = *(const bf16x8*)(&W1[wave * 32 + fr][ks * 32 + fq * 8]);
            bf16x8 b1 = *(const bf16x8*)(&W1[wave * 32 + 16 + fr][ks * 32 + fq * 8]);
            acc[0][0] = __builtin_amdgcn_mfma_f32_16x16x32_bf16(a0, b0, acc[0][0], 0, 0, 0);
            acc[0][1] = __builtin_amdgcn_mfma_f32_16x16x32_bf16(a0, b1, acc[0][1], 0, 0, 0);
            acc[1][0] = __builtin_amdgcn_mfma_f32_16x16x32_bf16(a1, b0, acc[1][0], 0, 0, 0);
            acc[1][1] = __builtin_amdgcn_mfma_f32_16x16x32_bf16(a1, b1, acc[1][1], 0, 0, 0);
        }
        __syncthreads();
    }
#pragma unroll
    for (int mi = 0; mi < 2; mi++)
#pragma unroll
        for (int ni = 0; ni < 2; ni++) {
            int col = wave * 32 + ni * 16 + fr;
            float bias = gb1[col];
#pragma unroll
            for (int r = 0; r < 4; r++) {
                int row = mi * 16 + fq * 4 + r;
                float v = acc[mi][ni][r] + bias;
                H[row][col] = 0.5f * v * (1.0f + erff(v * 0.70710678118f));
            }
        }
    __syncthreads();
    {
        int r = wave * 8 + (lane >> 3), g = lane & 7;
        float s = 0.f;
#pragma unroll
        for (int i = 0; i < 16; i++) { int c = g + i * 8; s += H[r][c] * gw2[c]; }
        s += __shfl_xor(s, 1); s += __shfl_xor(s, 2); s += __shfl_xor(s, 4);
        if (g == 0) {
            float aw = 1.0f / (1.0f + expf(-alpha[0]));
            float gt = 1.0f / (1.0f + expf(-(s + gb2[0])));
            scl[r] = gt * aw + (1.0f - aw);
        }
    }
    __syncthreads();
#pragma unroll
    for (int it = 0; it < 16; it++) {
        int r = it * 2 + (t >> 7);
        int c4 = (t & 127) * 4;
        bf16x4 b = *(const bf16x4*)(&F[r][c4]);
        float sc = scl[r];
        bf16x4 o = { (bf16)((float)b[0] * sc), (bf16)((float)b[1] * sc),
                     (bf16)((float)b[2] * sc), (bf16)((float)b[3] * sc) };
        *(bf16x4*)(Fs + (size_t)(m0 + r) * 512 + c4) = o;
    }
}

// ============ kernel C: QKV GEMM (y<24) + affinities (y==24) ============
__launch_bounds__(256)
__global__ void k_qkv(const bf16* __restrict__ A, const bf16* __restrict__ W,
                      const float* __restrict__ cwp, float* __restrict__ out,
                      float* __restrict__ aff, int M) {
    __shared__ bf16 As[2][128 * 32];
    __shared__ bf16 Bs[2][128 * 32];
    const int t = threadIdx.x, wave = t >> 6, lane = t & 63;
    const int fr = lane & 15, fq = lane >> 4;

    if (blockIdx.y == 24) {
        // ---- affinity path: reduce cw partials -> swizzled LDS tile, tiny MFMA ----
        bf16* cwt = (bf16*)As;    // [16 rows][512 cols], XOR-swizzled 16B chunks
        for (int e = t; e < 16 * 512; e += 256) {
            int v = e >> 9, c = e & 511;
            float s = 0.f;
            if (v < 10) {
#pragma unroll
                for (int cb = 0; cb < NCW; cb++)
                    s += cwp[((size_t)cb * 10 + v) * 512 + c];
            }
            int byte = v * 1024 + ((((c >> 3) ^ (v & 7)) << 4)) + (c & 7) * 2;
            *(bf16*)((char*)cwt + byte) = (bf16)s;
        }
        __syncthreads();
        const int m0w = blockIdx.x * 128 + wave * 32;
        f32x4 acc0 = (f32x4){0.f, 0.f, 0.f, 0.f};
        f32x4 acc1 = (f32x4){0.f, 0.f, 0.f, 0.f};
        for (int k0 = 0; k0 < 512; k0 += 32) {
            int chunk = (k0 >> 3) + fq;
            bf16x8 b = *(const bf16x8*)((char*)cwt + fr * 1024 + ((chunk ^ (fr & 7)) << 4));
            bf16x8 a0 = *(const bf16x8*)(A + (size_t)(m0w + fr) * 512 + k0 + fq * 8);
            bf16x8 a1 = *(const bf16x8*)(A + (size_t)(m0w + 16 + fr) * 512 + k0 + fq * 8);
            acc0 = __builtin_amdgcn_mfma_f32_16x16x32_bf16(a0, b, acc0, 0, 0, 0);
            acc1 = __builtin_amdgcn_mfma_f32_16x16x32_bf16(a1, b, acc1, 0, 0, 0);
        }
        if (fr < 10) {
#pragma unroll
            for (int r = 0; r < 4; r++) {
                int m = m0w + fq * 4 + r;
                if (m < M) aff[(size_t)fr * M + m] = acc0[r];
                m += 16;
                if (m < M) aff[(size_t)fr * M + m] = acc1[r];
            }
        }
        return;
    }

    const int m0 = blockIdx.x * 128, n0 = blockIdx.y * 128;
    const int wr = wave >> 1, wc = wave & 1;

    f32x4 acc[4][4];
#pragma unroll
    for (int i = 0; i < 4; i++)
#pragma unroll
        for (int j = 0; j < 4; j++) acc[i][j] = (f32x4){0.f, 0.f, 0.f, 0.f};

    const bf16* ga = A + (size_t)(m0 + (t >> 2)) * 512 + (t & 3) * 8;
    const bf16* gb = W + (size_t)(n0 + (t >> 2)) * 512 + (t & 3) * 8;

#define STAGE(buf, ko)                                              \
    gl_lds16(ga + (ko),            &As[buf][wave * 512]);           \
    gl_lds16(ga + (ko) + 64 * 512, &As[buf][2048 + wave * 512]);    \
    gl_lds16(gb + (ko),            &Bs[buf][wave * 512]);           \
    gl_lds16(gb + (ko) + 64 * 512, &Bs[buf][2048 + wave * 512]);

    STAGE(0, 0);
    __syncthreads();
    int cur = 0;
    for (int kt = 0; kt < 16; kt++) {
        if (kt < 15) { STAGE(cur ^ 1, (kt + 1) * 32); }
        bf16x8 af[4], bw[4];
#pragma unroll
        for (int mi = 0; mi < 4; mi++)
            af[mi] = *(const bf16x8*)(&As[cur][(wr * 64 + mi * 16 + fr) * 32 + fq * 8]);
#pragma unroll
        for (int ni = 0; ni < 4; ni++)
            bw[ni] = *(const bf16x8*)(&Bs[cur][(wc * 64 + ni * 16 + fr) * 32 + fq * 8]);
#pragma unroll
        for (int mi = 0; mi < 4; mi++)
#pragma unroll
            for (int ni = 0; ni < 4; ni++)
                acc[mi][ni] = __builtin_amdgcn_mfma_f32_16x16x32_bf16(af[mi], bw[ni], acc[mi][ni], 0, 0, 0);
        __syncthreads();
        cur ^= 1;
    }
#undef STAGE

    const int z = blockIdx.y >> 3;
    const int nb = (blockIdx.y & 7) * 128;
    float* obase = out + (size_t)z * M * EXPERT_DIM;
#pragma unroll
    for (int mi = 0; mi < 4; mi++)
#pragma unroll
        for (int ni = 0; ni < 4; ni++) {
            int col = nb + wc * 64 + ni * 16 + fr;
#pragma unroll
            for (int r = 0; r < 4; r++) {
                int row = m0 + wr * 64 + mi * 16 + fq * 4 + r;
                if (row < M) obase[(size_t)row * EXPERT_DIM + col] = acc[mi][ni][r];
            }
        }
}

extern "C" void kernel_launch(void* const* d_in, const int* in_sizes, int n_in,
                              void* d_out, int out_size, void* d_ws, size_t ws_size,
                              hipStream_t stream) {
    const float* tokens = (const float*)d_in[0];
    const float* fps    = (const float*)d_in[1];
    const float* alpha  = (const float*)d_in[2];
    const float* gw1    = (const float*)d_in[3];
    const float* gb1    = (const float*)d_in[4];
    const float* gw2    = (const float*)d_in[5];
    const float* gb2    = (const float*)d_in[6];
    const float* wq     = (const float*)d_in[7];
    const float* wk     = (const float*)d_in[8];
    const float* wv     = (const float*)d_in[9];
    const float* penta  = (const float*)d_in[10];
    float* out = (float*)d_out;

    int p = (out_size - P_TOK) / (3 * BATCH * EXPERT_DIM + 2 * 5 * BATCH);  // 12328
    if (p <= 0) return;
    int M = BATCH * p;
    int Mpad = (M + 127) & ~127;

    char* ws = (char*)d_ws;
    size_t off = 0;
    int*   idx   = (int*)(ws + off);   off += 16 * 1024;
    bf16*  wqkvb = (bf16*)(ws + off);  off += (size_t)3 * EXPERT_DIM * SLICE * 2;
    bf16*  w1b   = (bf16*)(ws + off);  off += (size_t)GATE_HID * SLICE * 2;
    float* cwp   = (float*)(ws + off); off += (size_t)NCW * 10 * 512 * 4;
    bf16*  Fs    = (bf16*)(ws + off);  off += (size_t)Mpad * SLICE * 2;
    (void)ws_size;

    float* aff_out  = out + (size_t)3 * M * EXPERT_DIM;
    float* mask_out = aff_out + (size_t)10 * M;

    k_setup<<<NCONV + 1 + NCW, 256, 0, stream>>>(wq, wk, wv, gw1, penta, fps,
                                                 wqkvb, w1b, cwp, mask_out, idx);
    k_gate<<<Mpad / 32, 256, 0, stream>>>(tokens, idx, w1b, gb1, gw2, gb2, alpha, p, M, Fs);
    k_qkv<<<dim3(Mpad / 128, 25), 256, 0, stream>>>(Fs, wqkvb, cwp, out, aff_out, M);
}

// Round 5
// 49.588 us; speedup vs baseline: 3.1620x; 1.2021x over previous
//
#include <hip/hip_runtime.h>
#include <hip/hip_bf16.h>

#define FULL_DIM 4096
#define EXPERT_DIM 1024
#define SLICE 512
#define S0 (3*SLICE)
#define GATE_HID 128
#define P_TOK 4096
#define BATCH 4
#define NCONV 1536   // 3*1024*512 elems / (256 thr * 4)
#define NCW 16       // cw partial blocks (64 d-values each)

typedef __bf16 bf16;
typedef __bf16 bf16x4 __attribute__((ext_vector_type(4)));
typedef __bf16 bf16x8 __attribute__((ext_vector_type(8)));
typedef float f32x4 __attribute__((ext_vector_type(4)));

__device__ inline void gl_lds16(const void* g, void* l) {
    __builtin_amdgcn_global_load_lds((const __attribute__((address_space(1))) void*)g,
                                     (__attribute__((address_space(3))) void*)l, 16, 0, 0);
}

// ============ kernel 1: gate blocks + mask + cw partials + weight converts ============
// bid in [0, ngate)          : gather + gate MLP + scale (self-contained mask scan)
// bid == ngate               : mask_out write
// bid in (ngate, ngate+NCW]  : cw partials (dirs . wk/wq chunks)
// bid > ngate+NCW            : f32->bf16 converts of wq|wk|wv
__launch_bounds__(256)
__global__ void k_front(const float* __restrict__ tokens, const float* __restrict__ fp,
                        const float* __restrict__ alpha,
                        const float* __restrict__ gw1, const float* __restrict__ gb1,
                        const float* __restrict__ gw2, const float* __restrict__ gb2,
                        const float* __restrict__ wq, const float* __restrict__ wk,
                        const float* __restrict__ wv, const float* __restrict__ penta,
                        bf16* __restrict__ wqkvb, float* __restrict__ cwp,
                        float* __restrict__ mask_out, bf16* __restrict__ Fs,
                        int p, int M, int ngate) {
    __shared__ bf16 F[32][520];
    __shared__ union { bf16 W1[128][72]; float H[32][132]; } u;
    __shared__ int trow[32];
    __shared__ float scl[32];
    __shared__ int sOffs[256];
    __shared__ unsigned short sBits[256];
    __shared__ int wsum[4];
    __shared__ float sd[5][64];
    __shared__ float red[5][4];
    const int bid = blockIdx.x, t = threadIdx.x;
    const int wave = t >> 6, lane = t & 63;

    if (bid < ngate) {
        // ---------- gate block ----------
        const int fr = lane & 15, fq = lane >> 4;
        const int m0 = bid * 32;
        // parallel mask scan (all blocks redundantly; fp is L2-hot)
        {
            int base = t * 16;
            unsigned bits = 0;
            int cnt = 0;
#pragma unroll
            for (int i = 0; i < 16; i++) {
                float v = fp[base + i];
                bool m = (v >= 0.375f) && (v < 0.5f);
                bits |= ((unsigned)m) << i;
                cnt += (int)m;
            }
            int incl = cnt;
#pragma unroll
            for (int d = 1; d < 64; d <<= 1) {
                int n = __shfl_up(incl, d);
                if (lane >= d) incl += n;
            }
            if (lane == 63) wsum[wave] = incl;
            __syncthreads();
            int wbase = 0;
            for (int w = 0; w < 4; w++) if (w < wave) wbase += wsum[w];
            sOffs[t] = wbase + incl - cnt;
            sBits[t] = (unsigned short)bits;
        }
        __syncthreads();
        if (t < 32) {
            int m = m0 + t;
            int r = -1;
            if (m < M) {
                int b = m / p, j = m - b * p;
                int lo = 0, hi = 255;
                while (lo < hi) { int mid = (lo + hi + 1) >> 1; if (sOffs[mid] <= j) lo = mid; else hi = mid - 1; }
                int jj = j - sOffs[lo];
                unsigned bt = sBits[lo];
                int pos = 0;
#pragma unroll
                for (int bit = 0; bit < 16; bit++) {
                    if ((bt >> bit) & 1) { if (jj == 0) { pos = bit; break; } jj--; }
                }
                r = b * P_TOK + lo * 16 + pos;
            }
            trow[t] = r;
        }
        __syncthreads();
        // gather expert slice -> bf16 LDS
#pragma unroll
        for (int it = 0; it < 16; it++) {
            int r = it * 2 + (t >> 7);
            int c4 = (t & 127) * 4;
            int tr = trow[r];
            float4 v = {0.f, 0.f, 0.f, 0.f};
            if (tr >= 0) v = *(const float4*)(tokens + (size_t)tr * FULL_DIM + S0 + c4);
            bf16x4 b = { (bf16)v.x, (bf16)v.y, (bf16)v.z, (bf16)v.w };
            *(bf16x4*)(&F[r][c4]) = b;
        }
        __syncthreads();
        // gate layer 1: H = GELU(F @ gw1^T + b1), gw1 converted inline while staging
        f32x4 acc[2][2];
#pragma unroll
        for (int i = 0; i < 2; i++)
#pragma unroll
            for (int j = 0; j < 2; j++) acc[i][j] = (f32x4){0.f, 0.f, 0.f, 0.f};
        for (int k0 = 0; k0 < 512; k0 += 64) {
            {
                int n = t >> 1, ch = (t & 1) * 32;
                const float* src = gw1 + (size_t)n * 512 + k0 + ch;
#pragma unroll
                for (int q = 0; q < 4; q++) {
                    float4 a = *(const float4*)(src + q * 8);
                    float4 b = *(const float4*)(src + q * 8 + 4);
                    bf16x8 w = { (bf16)a.x, (bf16)a.y, (bf16)a.z, (bf16)a.w,
                                 (bf16)b.x, (bf16)b.y, (bf16)b.z, (bf16)b.w };
                    *(bf16x8*)(&u.W1[n][ch + q * 8]) = w;
                }
            }
            __syncthreads();
#pragma unroll
            for (int ks = 0; ks < 2; ks++) {
                bf16x8 a0 = *(const bf16x8*)(&F[fr][k0 + ks * 32 + fq * 8]);
                bf16x8 a1 = *(const bf16x8*)(&F[16 + fr][k0 + ks * 32 + fq * 8]);
                bf16x8 b0 = *(const bf16x8*)(&u.W1[wave * 32 + fr][ks * 32 + fq * 8]);
                bf16x8 b1 = *(const bf16x8*)(&u.W1[wave * 32 + 16 + fr][ks * 32 + fq * 8]);
                acc[0][0] = __builtin_amdgcn_mfma_f32_16x16x32_bf16(a0, b0, acc[0][0], 0, 0, 0);
                acc[0][1] = __builtin_amdgcn_mfma_f32_16x16x32_bf16(a0, b1, acc[0][1], 0, 0, 0);
                acc[1][0] = __builtin_amdgcn_mfma_f32_16x16x32_bf16(a1, b0, acc[1][0], 0, 0, 0);
                acc[1][1] = __builtin_amdgcn_mfma_f32_16x16x32_bf16(a1, b1, acc[1][1], 0, 0, 0);
            }
            __syncthreads();
        }
        // epilogue: bias + exact GELU into H (aliases W1 -- all MFMA reads done)
#pragma unroll
        for (int mi = 0; mi < 2; mi++)
#pragma unroll
            for (int ni = 0; ni < 2; ni++) {
                int col = wave * 32 + ni * 16 + fr;
                float bias = gb1[col];
#pragma unroll
                for (int r = 0; r < 4; r++) {
                    int row = mi * 16 + fq * 4 + r;
                    float v = acc[mi][ni][r] + bias;
                    u.H[row][col] = 0.5f * v * (1.0f + erff(v * 0.70710678118f));
                }
            }
        __syncthreads();
        {
            int r = wave * 8 + (lane >> 3), g = lane & 7;
            float s = 0.f;
#pragma unroll
            for (int i = 0; i < 16; i++) { int c = g + i * 8; s += u.H[r][c] * gw2[c]; }
            s += __shfl_xor(s, 1); s += __shfl_xor(s, 2); s += __shfl_xor(s, 4);
            if (g == 0) {
                float aw = 1.0f / (1.0f + expf(-alpha[0]));
                float gt = 1.0f / (1.0f + expf(-(s + gb2[0])));
                scl[r] = gt * aw + (1.0f - aw);
            }
        }
        __syncthreads();
#pragma unroll
        for (int it = 0; it < 16; it++) {
            int r = it * 2 + (t >> 7);
            int c4 = (t & 127) * 4;
            bf16x4 b = *(const bf16x4*)(&F[r][c4]);
            float sc = scl[r];
            bf16x4 o = { (bf16)((float)b[0] * sc), (bf16)((float)b[1] * sc),
                         (bf16)((float)b[2] * sc), (bf16)((float)b[3] * sc) };
            *(bf16x4*)(Fs + (size_t)(m0 + r) * 512 + c4) = o;
        }
        return;
    }
    if (bid == ngate) {
        // ---------- mask output ----------
        int base = t * 16;
#pragma unroll
        for (int i = 0; i < 16; i++) {
            float v = fp[base + i];
            mask_out[base + i] = ((v >= 0.375f) && (v < 0.5f)) ? 1.0f : 0.0f;
        }
        return;
    }
    if (bid <= ngate + NCW) {
        // ---------- cw partial block ----------
        const int cb = bid - (ngate + 1);
        const int d0 = cb * 64;
#pragma unroll
        for (int v = 0; v < 5; v++) {
            float s = 0.f;
#pragma unroll
            for (int i = 0; i < 4; i++) { float x = penta[v * 1024 + t + i * 256]; s += x * x; }
            for (int d = 32; d; d >>= 1) s += __shfl_xor(s, d);
            if (lane == 0) red[v][wave] = s;
        }
        __syncthreads();
        for (int e = t; e < 5 * 64; e += 256) {
            int v = e >> 6, dd = e & 63;
            float inv = rsqrtf(red[v][0] + red[v][1] + red[v][2] + red[v][3]);
            sd[v][dd] = penta[v * 1024 + d0 + dd] * inv;
        }
        __syncthreads();
#pragma unroll
        for (int pass = 0; pass < 2; pass++) {
            int col = pass * 256 + t;
            float aK[5] = {0, 0, 0, 0, 0}, aQ[5] = {0, 0, 0, 0, 0};
            for (int d = 0; d < 64; d += 4) {
#pragma unroll
                for (int uu = 0; uu < 4; uu++) {
                    float kv = wk[(size_t)(d0 + d + uu) * 512 + col];
                    float qv = wq[(size_t)(d0 + d + uu) * 512 + col];
#pragma unroll
                    for (int v = 0; v < 5; v++) {
                        float dv = sd[v][d + uu];
                        aK[v] += dv * kv;
                        aQ[v] += dv * qv;
                    }
                }
            }
#pragma unroll
            for (int v = 0; v < 5; v++) {
                cwp[((size_t)cb * 10 + v) * 512 + col] = aK[v];
                cwp[((size_t)cb * 10 + 5 + v) * 512 + col] = aQ[v];
            }
        }
        return;
    }
    // ---------- weight converts ----------
    {
        int ci = bid - (ngate + 1 + NCW);
        int i = ci * 1024 + t * 4;
        const float* src = (i < 524288) ? wq : (i < 2 * 524288 ? wk : wv);
        float4 v = *(const float4*)(src + (i & 524287));
        bf16x4 b = { (bf16)v.x, (bf16)v.y, (bf16)v.z, (bf16)v.w };
        *(bf16x4*)(wqkvb + i) = b;
    }
}

// ============ kernel 2: QKV GEMM 256x128 (y<24) + affinities (y==24) ============
__launch_bounds__(512)
__global__ void k_qkv(const bf16* __restrict__ A, const bf16* __restrict__ W,
                      const float* __restrict__ cwp, float* __restrict__ out,
                      float* __restrict__ aff, int M) {
    __shared__ bf16 As[2][256 * 32];
    __shared__ bf16 Bs[2][128 * 32];
    const int t = threadIdx.x, wave = t >> 6, lane = t & 63;
    const int fr = lane & 15, fq = lane >> 4;

    if (blockIdx.y == 24) {
        // ---- affinity path: reduce cw partials -> swizzled LDS tile, tiny MFMA ----
        bf16* cwt = (bf16*)As;    // [16 rows][512 cols], XOR-swizzled 16B chunks
        for (int e = t; e < 16 * 512; e += 512) {
            int v = e >> 9, c = e & 511;
            float s = 0.f;
            if (v < 10) {
#pragma unroll
                for (int cb = 0; cb < NCW; cb++)
                    s += cwp[((size_t)cb * 10 + v) * 512 + c];
            }
            int byte = v * 1024 + ((((c >> 3) ^ (v & 7)) << 4)) + (c & 7) * 2;
            *(bf16*)((char*)cwt + byte) = (bf16)s;
        }
        __syncthreads();
        const int m0w = blockIdx.x * 256 + wave * 32;
        f32x4 acc0 = (f32x4){0.f, 0.f, 0.f, 0.f};
        f32x4 acc1 = (f32x4){0.f, 0.f, 0.f, 0.f};
        for (int k0 = 0; k0 < 512; k0 += 32) {
            int chunk = (k0 >> 3) + fq;
            bf16x8 b = *(const bf16x8*)((char*)cwt + fr * 1024 + ((chunk ^ (fr & 7)) << 4));
            bf16x8 a0 = *(const bf16x8*)(A + (size_t)(m0w + fr) * 512 + k0 + fq * 8);
            bf16x8 a1 = *(const bf16x8*)(A + (size_t)(m0w + 16 + fr) * 512 + k0 + fq * 8);
            acc0 = __builtin_amdgcn_mfma_f32_16x16x32_bf16(a0, b, acc0, 0, 0, 0);
            acc1 = __builtin_amdgcn_mfma_f32_16x16x32_bf16(a1, b, acc1, 0, 0, 0);
        }
        if (fr < 10) {
#pragma unroll
            for (int r = 0; r < 4; r++) {
                int m = m0w + fq * 4 + r;
                if (m < M) aff[(size_t)fr * M + m] = acc0[r];
                m += 16;
                if (m < M) aff[(size_t)fr * M + m] = acc1[r];
            }
        }
        return;
    }

    const int m0 = blockIdx.x * 256, n0 = blockIdx.y * 128;
    const int wr = wave >> 1, wc = wave & 1;

    f32x4 acc[4][4];
#pragma unroll
    for (int i = 0; i < 4; i++)
#pragma unroll
        for (int j = 0; j < 4; j++) acc[i][j] = (f32x4){0.f, 0.f, 0.f, 0.f};

    const bf16* ga = A + (size_t)(m0 + (t >> 2)) * 512 + (t & 3) * 8;
    const bf16* gb = W + (size_t)(n0 + (t >> 2)) * 512 + (t & 3) * 8;

#define STAGE(buf, ko)                                               \
    gl_lds16(ga + (ko),             &As[buf][wave * 512]);           \
    gl_lds16(ga + (ko) + 128 * 512, &As[buf][4096 + wave * 512]);    \
    gl_lds16(gb + (ko),             &Bs[buf][wave * 512]);

    STAGE(0, 0);
    __syncthreads();
    int cur = 0;
    for (int kt = 0; kt < 16; kt++) {
        if (kt < 15) { STAGE(cur ^ 1, (kt + 1) * 32); }
        bf16x8 af[4], bw[4];
#pragma unroll
        for (int mi = 0; mi < 4; mi++)
            af[mi] = *(const bf16x8*)(&As[cur][(wr * 64 + mi * 16 + fr) * 32 + fq * 8]);
#pragma unroll
        for (int ni = 0; ni < 4; ni++)
            bw[ni] = *(const bf16x8*)(&Bs[cur][(wc * 64 + ni * 16 + fr) * 32 + fq * 8]);
#pragma unroll
        for (int mi = 0; mi < 4; mi++)
#pragma unroll
            for (int ni = 0; ni < 4; ni++)
                acc[mi][ni] = __builtin_amdgcn_mfma_f32_16x16x32_bf16(af[mi], bw[ni], acc[mi][ni], 0, 0, 0);
        __syncthreads();
        cur ^= 1;
    }
#undef STAGE

    const int z = blockIdx.y >> 3;
    const int nb = (blockIdx.y & 7) * 128;
    float* obase = out + (size_t)z * M * EXPERT_DIM;
#pragma unroll
    for (int mi = 0; mi < 4; mi++)
#pragma unroll
        for (int ni = 0; ni < 4; ni++) {
            int col = nb + wc * 64 + ni * 16 + fr;
#pragma unroll
            for (int r = 0; r < 4; r++) {
                int row = m0 + wr * 64 + mi * 16 + fq * 4 + r;
                if (row < M) obase[(size_t)row * EXPERT_DIM + col] = acc[mi][ni][r];
            }
        }
}

extern "C" void kernel_launch(void* const* d_in, const int* in_sizes, int n_in,
                              void* d_out, int out_size, void* d_ws, size_t ws_size,
                              hipStream_t stream) {
    const float* tokens = (const float*)d_in[0];
    const float* fps    = (const float*)d_in[1];
    const float* alpha  = (const float*)d_in[2];
    const float* gw1    = (const float*)d_in[3];
    const float* gb1    = (const float*)d_in[4];
    const float* gw2    = (const float*)d_in[5];
    const float* gb2    = (const float*)d_in[6];
    const float* wq     = (const float*)d_in[7];
    const float* wk     = (const float*)d_in[8];
    const float* wv     = (const float*)d_in[9];
    const float* penta  = (const float*)d_in[10];
    float* out = (float*)d_out;

    int p = (out_size - P_TOK) / (3 * BATCH * EXPERT_DIM + 2 * 5 * BATCH);  // 12328
    if (p <= 0) return;
    int M = BATCH * p;
    int Mpad = (M + 255) & ~255;
    int ngate = Mpad / 32;

    char* ws = (char*)d_ws;
    size_t off = 0;
    bf16*  wqkvb = (bf16*)(ws + off);  off += (size_t)3 * EXPERT_DIM * SLICE * 2;
    float* cwp   = (float*)(ws + off); off += (size_t)NCW * 10 * 512 * 4;
    bf16*  Fs    = (bf16*)(ws + off);  off += (size_t)Mpad * SLICE * 2;
    (void)ws_size;

    float* aff_out  = out + (size_t)3 * M * EXPERT_DIM;
    float* mask_out = aff_out + (size_t)10 * M;

    k_front<<<ngate + 1 + NCW + NCONV, 256, 0, stream>>>(
        tokens, fps, alpha, gw1, gb1, gw2, gb2, wq, wk, wv, penta,
        wqkvb, cwp, mask_out, Fs, p, M, ngate);
    k_qkv<<<dim3(Mpad / 256, 25), 512, 0, stream>>>(Fs, wqkvb, cwp, out, aff_out, M);
}